// Round 12
// baseline (436.929 us; speedup 1.0000x reference)
//
#include <hip/hip_runtime.h>
#include <hip/hip_bf16.h>
#include <math.h>

typedef _Float16 f16;
typedef __attribute__((ext_vector_type(8))) _Float16 f16x8;
typedef __attribute__((ext_vector_type(4))) float f32x4;
typedef __attribute__((ext_vector_type(16))) float f32x16;
typedef __attribute__((ext_vector_type(4))) unsigned int u32x4;
typedef __attribute__((ext_vector_type(2))) unsigned int u32x2;

#define MFMA16(A, B, C) __builtin_amdgcn_mfma_f32_16x16x32_f16(A, B, C, 0, 0, 0)
#define MFMA32(A, B, C) __builtin_amdgcn_mfma_f32_32x32x16_f16(A, B, C, 0, 0, 0)
#define AS1 __attribute__((address_space(1)))
#define AS3 __attribute__((address_space(3)))

__device__ __forceinline__ void gld16(const char* g, char* l) {
  __builtin_amdgcn_global_load_lds((const AS1 void*)g, (AS3 void*)l, 16, 0, 0);
}

// single-instruction f32 pair -> packed f16 (RTZ); a -> low, b -> high
__device__ __forceinline__ unsigned pk2(float a, float b) {
  auto h = __builtin_amdgcn_cvt_pkrtz(a, b);   // __fp16 ext_vector(2)
  return __builtin_bit_cast(unsigned, h);
}

namespace {
constexpr int kB = 2048;
constexpr int kNch = 16, kChunk = 3125, kNit = 98;   // 98*32 = 3136 >= 3125
constexpr int kKRows = 50176;                        // padded K16 rows
constexpr int kVStride = 3200;                       // padded keys per chunk in Vt16
// workspace layout (bytes)
constexpr size_t WS_PROJ = 0;                                   // [2048][512] f32
constexpr size_t WS_QHI  = WS_PROJ + (size_t)2048 * 512 * 4;    // [2048][512] f16 (beta*log2e scaled)
constexpr size_t WS_M    = WS_QHI + (size_t)2048 * 512 * 2;     // [16][2048] f32 (log2 domain)
constexpr size_t WS_L    = WS_M + (size_t)kNch * kB * 4;        // [16][2048] f32
constexpr size_t WS_PV   = WS_L + (size_t)kNch * kB * 4;        // [16][2048][512] f16 (normalized)
constexpr size_t WS_K16  = WS_PV + (size_t)kNch * kB * 512 * 2; // [50176][512] f16
constexpr size_t WS_VT   = WS_K16 + (size_t)kKRows * 512 * 2;   // [16][512][3200] f16
// attn LDS layout
constexpr int LDS_K0 = 0, LDS_K1 = 33280;            // 2 x (32 rows x 1040B)
constexpr int LDS_V0 = 66560, LDS_V1 = 99328;        // 2 x (512 cols x 64B)
constexpr int LDS_S  = 132096;                       // 4 x 4096 (S-partial exchange)
constexpr int LDS_P  = 148480;                       // 4 x 2048 (P B-frags)
constexpr int LDS_FAC = 156672;                      // 128 f32
constexpr int LDS_FLG = 157184;                      // 4 int
constexpr int LDS_SZ  = 157696;
}

// ---------------------------------------------------------------------------
// K16: f16 copy of cache_image_features, rows >= 50000 zero-filled.
// ---------------------------------------------------------------------------
__global__ __launch_bounds__(256) void convk_kernel(const float* __restrict__ src,
                                                    f16* __restrict__ dst) {
  const size_t e = ((size_t)blockIdx.x * 256 + threadIdx.x) * 8;
  const int row = (int)(e >> 9);
  float4 a = make_float4(0.f, 0.f, 0.f, 0.f), b = a;
  if (row < 50000) {
    a = *(const float4*)(src + e);
    b = *(const float4*)(src + e + 4);
  }
  f16x8 h;
  h[0] = (f16)a.x; h[1] = (f16)a.y; h[2] = (f16)a.z; h[3] = (f16)a.w;
  h[4] = (f16)b.x; h[5] = (f16)b.y; h[6] = (f16)b.z; h[7] = (f16)b.w;
  *(f16x8*)(dst + e) = h;
}

// ---------------------------------------------------------------------------
// Vt16[ch][col][key] f16 transpose of cache_text_features; pad keys zeroed.
// ---------------------------------------------------------------------------
__global__ __launch_bounds__(256) void transv_kernel(const float* __restrict__ Vf,
                                                     f16* __restrict__ Vt) {
  __shared__ float tile[64][65];
  const int kt = blockIdx.x, colt = blockIdx.y, ch = blockIdx.z;
  const int t = threadIdx.x;
  const int kbase = kt * 64, col0 = colt * 64;
  {
    const int key = t >> 2, cseg = (t & 3) * 16;
    const int kk = kbase + key;
    float4 v0 = make_float4(0.f, 0.f, 0.f, 0.f), v1 = v0, v2 = v0, v3 = v0;
    if (kk < kChunk) {
      const float* s = Vf + (size_t)(ch * kChunk + kk) * 512 + col0 + cseg;
      v0 = *(const float4*)(s);
      v1 = *(const float4*)(s + 4);
      v2 = *(const float4*)(s + 8);
      v3 = *(const float4*)(s + 12);
    }
    float* tr = &tile[key][cseg];
    tr[0] = v0.x;  tr[1] = v0.y;  tr[2] = v0.z;  tr[3] = v0.w;
    tr[4] = v1.x;  tr[5] = v1.y;  tr[6] = v1.z;  tr[7] = v1.w;
    tr[8] = v2.x;  tr[9] = v2.y;  tr[10] = v2.z; tr[11] = v2.w;
    tr[12] = v3.x; tr[13] = v3.y; tr[14] = v3.z; tr[15] = v3.w;
  }
  __syncthreads();
  {
    const int col = t >> 2, kw = (t & 3) * 16;
    f16x8 h0, h1;
    #pragma unroll
    for (int u = 0; u < 8; u++) h0[u] = (f16)tile[kw + u][col];
    #pragma unroll
    for (int u = 0; u < 8; u++) h1[u] = (f16)tile[kw + 8 + u][col];
    f16* d = Vt + ((size_t)ch * 512 + col0 + col) * kVStride + kbase + kw;
    *(f16x8*)(d) = h0;
    *(f16x8*)(d + 8) = h1;
  }
}

// ---------------------------------------------------------------------------
// Kernel 1: proj = x @ W^T + b   (f16 x3-split MFMA, near-fp32 accuracy)
// qhi = proj * beta * log2(e)  (folds softmax scaling into Q once)
// ---------------------------------------------------------------------------
__global__ __launch_bounds__(256) void gemm1_kernel(
    const float* __restrict__ x, const float* __restrict__ W,
    const float* __restrict__ bias, const float* __restrict__ beta_p,
    float* __restrict__ proj, f16* __restrict__ qhi)
{
  __shared__ f16 xh[2][64][40], xl[2][64][40], wh[2][64][40], wl[2][64][40];
  const int t = threadIdx.x;
  const int lane = t & 63, w = t >> 6;
  const int wr = w >> 1, wc = w & 1;
  const int g = lane >> 4, j = lane & 15;
  const int m0 = blockIdx.x * 64, n0 = blockIdx.y * 64;
  const int srow = t >> 2;
  const int soff = (t & 3) * 8;
  const float bscale = beta_p[0] * 1.44269504f;

  const f32x4 fzero = {0.f, 0.f, 0.f, 0.f};
  f32x4 acc[2][2], acc2[2][2];
  #pragma unroll
  for (int a = 0; a < 2; a++)
    #pragma unroll
    for (int bb = 0; bb < 2; bb++) { acc[a][bb] = fzero; acc2[a][bb] = fzero; }

  auto stage = [&](int k0s, int buf) {
    const float* xs  = x + (size_t)(m0 + srow) * 1024 + k0s + soff;
    const float* wsr = W + (size_t)(n0 + srow) * 1024 + k0s + soff;
    f16x8 hx, lx, hw, lw;
    #pragma unroll
    for (int i = 0; i < 8; i++) {
      float v = xs[i];
      f16 h = (f16)v;
      hx[i] = h;
      lx[i] = (f16)((v - (float)h) * 2048.0f);
      float u = wsr[i];
      f16 hu = (f16)u;
      hw[i] = hu;
      lw[i] = (f16)((u - (float)hu) * 2048.0f);
    }
    *(f16x8*)&xh[buf][srow][soff] = hx;
    *(f16x8*)&xl[buf][srow][soff] = lx;
    *(f16x8*)&wh[buf][srow][soff] = hw;
    *(f16x8*)&wl[buf][srow][soff] = lw;
  };

  stage(0, 0);
  for (int ks = 0; ks < 32; ks++) {
    __syncthreads();
    if (ks < 31) stage((ks + 1) * 32, (ks + 1) & 1);
    const int buf = ks & 1;
    f16x8 ah[2], al[2], bh[2], bl[2];
    #pragma unroll
    for (int mf = 0; mf < 2; mf++) {
      const int r = wr * 32 + mf * 16 + j;
      ah[mf] = *(const f16x8*)&xh[buf][r][g * 8];
      al[mf] = *(const f16x8*)&xl[buf][r][g * 8];
      const int cc = wc * 32 + mf * 16 + j;
      bh[mf] = *(const f16x8*)&wh[buf][cc][g * 8];
      bl[mf] = *(const f16x8*)&wl[buf][cc][g * 8];
    }
    #pragma unroll
    for (int mf = 0; mf < 2; mf++)
      #pragma unroll
      for (int nf = 0; nf < 2; nf++) {
        acc[mf][nf]  = MFMA16(ah[mf], bh[nf], acc[mf][nf]);
        acc2[mf][nf] = MFMA16(ah[mf], bl[nf], acc2[mf][nf]);
        acc2[mf][nf] = MFMA16(al[mf], bh[nf], acc2[mf][nf]);
      }
  }

  #pragma unroll
  for (int mf = 0; mf < 2; mf++)
    #pragma unroll
    for (int nf = 0; nf < 2; nf++)
      #pragma unroll
      for (int r = 0; r < 4; r++) {
        const int m = m0 + wr * 32 + mf * 16 + g * 4 + r;
        const int n = n0 + wc * 32 + nf * 16 + j;
        float p = acc[mf][nf][r] + acc2[mf][nf][r] * (1.0f / 2048.0f) + bias[n];
        proj[(size_t)m * 512 + n] = p;
        qhi[(size_t)m * 512 + n] = (f16)(p * bscale);
      }
}

// ---------------------------------------------------------------------------
// Kernel 2: flash attention partial. R5-proven 2-phase schedule:
//   phase B: pvstep(it-1) FIRST, then stageK(it+1), then QK(it) + S-write
//   phase A: dh0 Sq-reads hoisted, stageV(it+1), softmax (exp2 domain)
// Cross-half sum deferred to epilogue; cross-half max only on rescale iters.
// 2 barriers/iter; vmcnt counted (4), never drained mid-loop.
// ---------------------------------------------------------------------------
__global__ __launch_bounds__(512, 2) void attn_kernel(
    const f16* __restrict__ K16, const f16* __restrict__ Vt16,
    const f16* __restrict__ qhi_ws,
    float* __restrict__ m_part, float* __restrict__ l_part,
    f16* __restrict__ pvn)
{
  extern __shared__ char smem[];
  const int t = threadIdx.x, lane = t & 63, w = t >> 6;
  const int c = lane & 31, h = lane >> 5;
  const int qb = w & 3, dh = w >> 2;     // QK / softmax roles
  const int qp = w & 1, cq = w >> 1;     // PV roles (cq 0..3)
  const int ch = blockIdx.x & 15, qt = blockIdx.x >> 4;
  const int q0 = qt * 128;

  char* const Kb0 = smem + LDS_K0;
  char* const Kb1 = smem + LDS_K1;
  char* const Vb0 = smem + LDS_V0;
  char* const Vb1 = smem + LDS_V1;
  char* const Sq  = smem + LDS_S + qb * 4096;   // own-qb S-partial slot
  char* const Pq  = smem + LDS_P + qb * 2048;   // own-qb P slot
  float* const facl = (float*)(smem + LDS_FAC);
  int* const flg = (int*)(smem + LDS_FLG);

  // ---- Q -> registers as B-frags: lane holds q-col = qb*32+c, k-chunk h*8.
  f16x8 Qf[16];
  {
    const f16* qsrc = qhi_ws + (size_t)(q0 + qb * 32 + c) * 512 + dh * 256 + h * 8;
    #pragma unroll
    for (int i = 0; i < 16; i++) Qf[i] = *(const f16x8*)(qsrc + i * 16);
  }
  __builtin_amdgcn_sched_barrier(0);

  const char* const Kg = (const char*)K16 + (size_t)(ch * kChunk) * 1024;
  const char* const Vg = (const char*)Vt16 + (size_t)ch * 512 * (kVStride * 2);
  // pre-swizzled V source chunk (matches read-side ((c>>1)&3) XOR)
  const int vlo = (((lane & 3) ^ ((lane >> 3) & 3)) << 4);

  auto stageK = [&](int it2, char* dstbuf) {
    const char* src = Kg + (size_t)(it2 * 32 + w * 4) * 1024 + lane * 16;
    char* dst = dstbuf + (w * 4) * 1040 + lane * 16;
    #pragma unroll
    for (int u = 0; u < 4; u++) gld16(src + u * 1024, dst + u * 1040);
  };
  auto stageV = [&](int it2, char* dstbuf) {
    const char* src = Vg + (size_t)(w * 64 + (lane >> 2)) * (kVStride * 2) + it2 * 64 + vlo;
    char* dst = dstbuf + (w * 4) * 1024 + lane * 16;
    #pragma unroll
    for (int u = 0; u < 4; u++)
      gld16(src + (size_t)(u * 16) * (kVStride * 2), dst + u * 1024);
  };

  // LDS read offsets (bank-conflict-engineered)
  const int kroff = c * 1040 + dh * 512 + h * 16;          // QK A-frag base
  const int vbase = (cq * 128 + c) * 64;                   // PV A-frag base
  const int vswz = ((c >> 1) & 3) << 4;
  const int voff0 = (0 + h * 16) ^ vswz;                   // keys 0..15
  const int voff1 = (32 + h * 16) ^ vswz;                  // keys 16..31
  const char* const slotA = smem + LDS_P + (2 * qp) * 2048 + lane * 16;
  const char* const slotB = smem + LDS_P + (2 * qp + 1) * 2048 + lane * 16;

  f32x16 O[2][4];
  #pragma unroll
  for (int ql = 0; ql < 2; ql++)
    #pragma unroll
    for (int cb = 0; cb < 4; cb++)
      #pragma unroll
      for (int r = 0; r < 16; r++) O[ql][cb][r] = 0.f;
  float mrow = -INFINITY, lrow = 0.f;   // lrow is HALF-local (combined in epilogue)

  // PV(prev) step: rescale (flag-gated) + 16 MFMA32 on V buffer `Vp`
  auto pvstep = [&](const char* Vp) {
    const int f0 = flg[2 * qp];
    const int f1 = flg[2 * qp + 1];
    const f16x8 pb00 = *(const f16x8*)(slotA);
    const f16x8 pb01 = *(const f16x8*)(slotA + 1024);
    const f16x8 pb10 = *(const f16x8*)(slotB);
    const f16x8 pb11 = *(const f16x8*)(slotB + 1024);
    if (f0) {
      const float fc0 = facl[(2 * qp) * 32 + c];
      #pragma unroll
      for (int cb = 0; cb < 4; cb++)
        #pragma unroll
        for (int r = 0; r < 16; r++) O[0][cb][r] *= fc0;
    }
    if (f1) {
      const float fc1 = facl[(2 * qp + 1) * 32 + c];
      #pragma unroll
      for (int cb = 0; cb < 4; cb++)
        #pragma unroll
        for (int r = 0; r < 16; r++) O[1][cb][r] *= fc1;
    }
    __builtin_amdgcn_s_setprio(1);
    #pragma unroll
    for (int cb = 0; cb < 4; cb++) {
      f16x8 a0 = *(const f16x8*)(Vp + cb * 2048 + voff0);
      f16x8 a1 = *(const f16x8*)(Vp + cb * 2048 + voff1);
      O[0][cb] = MFMA32(a0, pb00, O[0][cb]);
      O[0][cb] = MFMA32(a1, pb01, O[0][cb]);
      O[1][cb] = MFMA32(a0, pb10, O[1][cb]);
      O[1][cb] = MFMA32(a1, pb11, O[1][cb]);
    }
    __builtin_amdgcn_s_setprio(0);
  };

  // prologue: K0 + V0 in flight; wait K0 only
  stageK(0, Kb0);
  stageV(0, Vb0);
  asm volatile("s_waitcnt vmcnt(4)" ::: "memory");
  __builtin_amdgcn_s_barrier();

  for (int it = 0; it < kNit; it++) {
    const int p = it & 1;
    const char* const Kp = (p ? Kb1 : Kb0) + kroff;

    // ================= phase B: PV(it-1) first, then QK(it) =================
    if (it > 0) pvstep((p ? Vb0 : Vb1) + vbase);   // V[it-1] lives in buf p^1
    if (it + 1 < kNit) stageK(it + 1, p ? Kb0 : Kb1);

    f32x16 S;
    #pragma unroll
    for (int r = 0; r < 16; r++) S[r] = 0.f;
    __builtin_amdgcn_s_setprio(1);
    #pragma unroll
    for (int i = 0; i < 16; i++) {
      f16x8 a = *(const f16x8*)(Kp + i * 32);
      S = MFMA32(a, Qf[i], S);
    }
    __builtin_amdgcn_s_setprio(0);

    if (dh == 1) {  // write d-partial (f32), lane-major, conflict-free
      f32x4 v0 = {S[0], S[1], S[2], S[3]};
      f32x4 v1 = {S[4], S[5], S[6], S[7]};
      f32x4 v2 = {S[8], S[9], S[10], S[11]};
      f32x4 v3 = {S[12], S[13], S[14], S[15]};
      *(f32x4*)(Sq + 0 * 1024 + lane * 16) = v0;
      *(f32x4*)(Sq + 1 * 1024 + lane * 16) = v1;
      *(f32x4*)(Sq + 2 * 1024 + lane * 16) = v2;
      *(f32x4*)(Sq + 3 * 1024 + lane * 16) = v3;
    }
    asm volatile("s_waitcnt lgkmcnt(0)" ::: "memory");
    __builtin_amdgcn_s_barrier();                         // bar-beta

    // ================= phase A: Sq-reads -> stageV -> softmax(it) =========
    f32x4 sp0, sp1, sp2, sp3;
    if (dh == 0) {   // issue S-partial reads FIRST (latency under stageV issue)
      sp0 = *(const f32x4*)(Sq + 0 * 1024 + lane * 16);
      sp1 = *(const f32x4*)(Sq + 1 * 1024 + lane * 16);
      sp2 = *(const f32x4*)(Sq + 2 * 1024 + lane * 16);
      sp3 = *(const f32x4*)(Sq + 3 * 1024 + lane * 16);
    }
    if (it + 1 < kNit) stageV(it + 1, p ? Vb0 : Vb1);     // after bar: safe vs PV reads

    if (dh == 0) {
      S[0] += sp0.x;  S[1] += sp0.y;  S[2] += sp0.z;  S[3] += sp0.w;
      S[4] += sp1.x;  S[5] += sp1.y;  S[6] += sp1.z;  S[7] += sp1.w;
      S[8] += sp2.x;  S[9] += sp2.y;  S[10] += sp2.z; S[11] += sp2.w;
      S[12] += sp3.x; S[13] += sp3.y; S[14] += sp3.z; S[15] += sp3.w;
      // S already in log2 domain (beta*log2e folded into qhi)
      if (it == kNit - 1) {
        #pragma unroll
        for (int r = 0; r < 16; r++) {
          const int key = it * 32 + (r & 3) + 8 * (r >> 2) + 4 * h;
          if (key >= kChunk) S[r] = -INFINITY;
        }
      }
      // depth-4 max tree (half-local)
      float t0 = fmaxf(S[0], S[1]),  t1 = fmaxf(S[2], S[3]);
      float t2 = fmaxf(S[4], S[5]),  t3 = fmaxf(S[6], S[7]);
      float t4 = fmaxf(S[8], S[9]),  t5 = fmaxf(S[10], S[11]);
      float t6 = fmaxf(S[12], S[13]), t7 = fmaxf(S[14], S[15]);
      t0 = fmaxf(t0, t1); t2 = fmaxf(t2, t3);
      t4 = fmaxf(t4, t5); t6 = fmaxf(t6, t7);
      t0 = fmaxf(t0, t2); t4 = fmaxf(t4, t6);
      float pm = fmaxf(t0, t4);
      // __any spans all 64 lanes -> half-local pm suffices as trigger
      const int need = __any(pm > mrow + 11.5416f);       // defer-max (T13, =e^8)
      float fc = 1.0f;
      if (need) {
        pm = fmaxf(pm, __shfl_xor(pm, 32));               // full-row max (rare)
        const float mn = fmaxf(mrow, pm);
        fc = exp2f(mrow - mn);
        mrow = mn;
      }
      float pr[16];
      #pragma unroll
      for (int r = 0; r < 16; r++) pr[r] = exp2f(S[r] - mrow);
      // depth-4 sum tree; lrow stays HALF-local (combined once in epilogue)
      float s0 = (pr[0] + pr[1]) + (pr[2] + pr[3]);
      float s1 = (pr[4] + pr[5]) + (pr[6] + pr[7]);
      float s2 = (pr[8] + pr[9]) + (pr[10] + pr[11]);
      float s3 = (pr[12] + pr[13]) + (pr[14] + pr[15]);
      float rs = (s0 + s1) + (s2 + s3);
      lrow = lrow * fc + rs;
      // build PV B-frags (pack + half-shuffle + select; known-good layout)
      unsigned pA0 = pk2(pr[0], pr[1]),  pA1 = pk2(pr[2], pr[3]);
      unsigned pB0 = pk2(pr[4], pr[5]),  pB1 = pk2(pr[6], pr[7]);
      unsigned pC0 = pk2(pr[8], pr[9]),  pC1 = pk2(pr[10], pr[11]);
      unsigned pD0 = pk2(pr[12], pr[13]), pD1 = pk2(pr[14], pr[15]);
      unsigned sA0 = __shfl_xor(pA0, 32), sA1 = __shfl_xor(pA1, 32);
      unsigned sB0 = __shfl_xor(pB0, 32), sB1 = __shfl_xor(pB1, 32);
      unsigned sC0 = __shfl_xor(pC0, 32), sC1 = __shfl_xor(pC1, 32);
      unsigned sD0 = __shfl_xor(pD0, 32), sD1 = __shfl_xor(pD1, 32);
      u32x4 B0, B1;
      B0[0] = h ? sB0 : pA0;  B0[1] = h ? sB1 : pA1;
      B0[2] = h ? pB0 : sA0;  B0[3] = h ? pB1 : sA1;
      B1[0] = h ? sD0 : pC0;  B1[1] = h ? sD1 : pC1;
      B1[2] = h ? pD0 : sC0;  B1[3] = h ? pD1 : sC1;
      *(u32x4*)(Pq + lane * 16) = B0;
      *(u32x4*)(Pq + 1024 + lane * 16) = B1;
      if (need && h == 0) facl[qb * 32 + c] = fc;
      if (lane == 0) flg[qb] = need;
    }
    if (it + 1 < kNit)
      asm volatile("s_waitcnt lgkmcnt(0) vmcnt(4)" ::: "memory");  // K(it+1)+V(it) landed
    else
      asm volatile("s_waitcnt lgkmcnt(0) vmcnt(0)" ::: "memory");
    __builtin_amdgcn_s_barrier();                         // bar-alpha
  }

  // final PV of the last slab (V[kNit-1] in buffer (kNit-1)&1)
  pvstep((((kNit - 1) & 1) ? Vb1 : Vb0) + vbase);

  // ---------------- epilogue ----------------
  asm volatile("s_waitcnt lgkmcnt(0)" ::: "memory");
  __builtin_amdgcn_s_barrier();   // all pvstep facl/P reads done before overwrite
  if (dh == 0) {
    lrow += __shfl_xor(lrow, 32);   // combine half-local sums ONCE
    const float iv = 1.0f / lrow;
    if (lane < 32) {
      m_part[ch * kB + q0 + qb * 32 + c] = mrow;
      l_part[ch * kB + q0 + qb * 32 + c] = lrow;
      facl[qb * 32 + c] = iv;
    }
  }
  asm volatile("s_waitcnt lgkmcnt(0)" ::: "memory");
  __builtin_amdgcn_s_barrier();
  const float iv0 = facl[(2 * qp) * 32 + c];
  const float iv1 = facl[(2 * qp + 1) * 32 + c];

  const size_t pvb = ((size_t)ch * kB + q0) * 512;
  #pragma unroll
  for (int ql = 0; ql < 2; ql++) {
    const int qrow = (2 * qp + ql) * 32 + c;
    const float iv = ql ? iv1 : iv0;
    #pragma unroll
    for (int cb = 0; cb < 4; cb++) {
      const int C = cq * 128 + cb * 32;
      #pragma unroll
      for (int a = 0; a < 4; a++) {
        unsigned lo = pk2(O[ql][cb][4 * a + 0] * iv, O[ql][cb][4 * a + 1] * iv);
        unsigned hi = pk2(O[ql][cb][4 * a + 2] * iv, O[ql][cb][4 * a + 3] * iv);
        u32x2 v = {lo, hi};
        *(u32x2*)(pvn + pvb + (size_t)qrow * 512 + C + 8 * a + 4 * h) = v;
      }
    }
  }
}

// ---------------------------------------------------------------------------
// Kernel 3: combine (m in log2 domain):
//   out = proj + alpha * (sum_c g_c l_c pvn_c) / (sum_c g_c l_c), g_c = 2^(m_c-M)
// ---------------------------------------------------------------------------
__global__ __launch_bounds__(256) void combine_kernel(
    const float* __restrict__ proj, const float* __restrict__ m_part,
    const float* __restrict__ l_part, const f16* __restrict__ pvn,
    const float* __restrict__ alpha_p, float* __restrict__ out)
{
  const int row = blockIdx.x;
  const int t = threadIdx.x;
  const float alpha = alpha_p[0];
  float M = -INFINITY;
  #pragma unroll
  for (int c = 0; c < kNch; c++) M = fmaxf(M, m_part[c * kB + row]);
  float gl[kNch];
  float T = 0.f;
  #pragma unroll
  for (int c = 0; c < kNch; c++) {
    gl[c] = exp2f(m_part[c * kB + row] - M) * l_part[c * kB + row];
    T += gl[c];
  }
  const float s = alpha / T;
  #pragma unroll
  for (int half = 0; half < 2; half++) {
    const int col = t + half * 256;
    float acc = 0.f;
    #pragma unroll
    for (int c = 0; c < kNch; c++)
      acc += gl[c] * (float)pvn[((size_t)c * kB + row) * 512 + col];
    out[(size_t)row * 512 + col] = proj[(size_t)row * 512 + col] + acc * s;
  }
}

// ---------------------------------------------------------------------------
extern "C" void kernel_launch(void* const* d_in, const int* in_sizes, int n_in,
                              void* d_out, int out_size, void* d_ws, size_t ws_size,
                              hipStream_t stream) {
  (void)in_sizes; (void)n_in; (void)out_size; (void)ws_size;
  const float* x     = (const float*)d_in[0];
  const float* W     = (const float*)d_in[1];
  const float* bias  = (const float*)d_in[2];
  const float* cimg  = (const float*)d_in[3];
  const float* ctxt  = (const float*)d_in[4];
  const float* beta  = (const float*)d_in[5];
  const float* alpha = (const float*)d_in[6];
  float* out = (float*)d_out;
  char* ws = (char*)d_ws;

  float* proj = (float*)(ws + WS_PROJ);
  f16*   qhi  = (f16*)(ws + WS_QHI);
  float* mp   = (float*)(ws + WS_M);
  float* lp   = (float*)(ws + WS_L);
  f16*   pvn  = (f16*)(ws + WS_PV);
  f16*   K16  = (f16*)(ws + WS_K16);
  f16*   Vt16 = (f16*)(ws + WS_VT);

  (void)hipFuncSetAttribute((const void*)attn_kernel,
                            hipFuncAttributeMaxDynamicSharedMemorySize, LDS_SZ);

  convk_kernel<<<(kKRows * 512 / 8 + 255) / 256, 256, 0, stream>>>(cimg, K16);
  transv_kernel<<<dim3(kVStride / 64, 8, kNch), 256, 0, stream>>>(ctxt, Vt16);
  gemm1_kernel<<<dim3(32, 8), 256, 0, stream>>>(x, W, bias, beta, proj, qhi);
  attn_kernel<<<256, 512, LDS_SZ, stream>>>(K16, Vt16, qhi, mp, lp, pvn);
  combine_kernel<<<2048, 256, 0, stream>>>(proj, mp, lp, pvn, alpha, out);
}

// Round 13
// 362.928 us; speedup vs baseline: 1.2039x; 1.2039x over previous
//
#include <hip/hip_runtime.h>
#include <hip/hip_bf16.h>
#include <math.h>

typedef _Float16 f16;
typedef __attribute__((ext_vector_type(8))) _Float16 f16x8;
typedef __attribute__((ext_vector_type(4))) float f32x4;
typedef __attribute__((ext_vector_type(16))) float f32x16;
typedef __attribute__((ext_vector_type(4))) unsigned int u32x4;
typedef __attribute__((ext_vector_type(2))) unsigned int u32x2;

#define MFMA16(A, B, C) __builtin_amdgcn_mfma_f32_16x16x32_f16(A, B, C, 0, 0, 0)
#define MFMA32(A, B, C) __builtin_amdgcn_mfma_f32_32x32x16_f16(A, B, C, 0, 0, 0)
#define AS1 __attribute__((address_space(1)))
#define AS3 __attribute__((address_space(3)))

__device__ __forceinline__ void gld16(const char* g, char* l) {
  __builtin_amdgcn_global_load_lds((const AS1 void*)g, (AS3 void*)l, 16, 0, 0);
}

// single-instruction f32 pair -> packed f16 (RTZ); a -> low, b -> high
__device__ __forceinline__ unsigned pk2(float a, float b) {
  auto h = __builtin_amdgcn_cvt_pkrtz(a, b);   // __fp16 ext_vector(2)
  return __builtin_bit_cast(unsigned, h);
}

namespace {
constexpr int kB = 2048;
constexpr int kNch = 16, kChunk = 3125, kNit = 98;   // 98*32 = 3136 >= 3125
constexpr int kKRows = 50176;                        // padded K16 rows
constexpr int kVStride = 3200;                       // padded keys per chunk in Vt16
// workspace layout (bytes)
constexpr size_t WS_PROJ = 0;                                   // [2048][512] f32
constexpr size_t WS_QHI  = WS_PROJ + (size_t)2048 * 512 * 4;    // [2048][512] f16 (beta*log2e scaled)
constexpr size_t WS_M    = WS_QHI + (size_t)2048 * 512 * 2;     // [16][2048] f32 (log2 domain)
constexpr size_t WS_L    = WS_M + (size_t)kNch * kB * 4;        // [16][2048] f32
constexpr size_t WS_PV   = WS_L + (size_t)kNch * kB * 4;        // [16][2048][512] f16 (normalized)
constexpr size_t WS_K16  = WS_PV + (size_t)kNch * kB * 512 * 2; // [50176][512] f16
constexpr size_t WS_VT   = WS_K16 + (size_t)kKRows * 512 * 2;   // [16][512][3200] f16
// attn LDS layout
constexpr int LDS_K0 = 0, LDS_K1 = 33280;            // 2 x (32 rows x 1040B)
constexpr int LDS_V0 = 66560, LDS_V1 = 99328;        // 2 x (512 cols x 64B)
constexpr int LDS_S  = 132096;                       // 4 x 4096 (S-partial exchange)
constexpr int LDS_P  = 148480;                       // 4 x 2048 (P B-frags)
constexpr int LDS_FAC = 156672;                      // 128 f32
constexpr int LDS_FLG = 157184;                      // 4 int
constexpr int LDS_SZ  = 157696;
}

// ---------------------------------------------------------------------------
// K16: f16 copy of cache_image_features, rows >= 50000 zero-filled.
// ---------------------------------------------------------------------------
__global__ __launch_bounds__(256) void convk_kernel(const float* __restrict__ src,
                                                    f16* __restrict__ dst) {
  const size_t e = ((size_t)blockIdx.x * 256 + threadIdx.x) * 8;
  const int row = (int)(e >> 9);
  float4 a = make_float4(0.f, 0.f, 0.f, 0.f), b = a;
  if (row < 50000) {
    a = *(const float4*)(src + e);
    b = *(const float4*)(src + e + 4);
  }
  f16x8 h;
  h[0] = (f16)a.x; h[1] = (f16)a.y; h[2] = (f16)a.z; h[3] = (f16)a.w;
  h[4] = (f16)b.x; h[5] = (f16)b.y; h[6] = (f16)b.z; h[7] = (f16)b.w;
  *(f16x8*)(dst + e) = h;
}

// ---------------------------------------------------------------------------
// Vt16[ch][col][key] f16 transpose of cache_text_features; pad keys zeroed.
// ---------------------------------------------------------------------------
__global__ __launch_bounds__(256) void transv_kernel(const float* __restrict__ Vf,
                                                     f16* __restrict__ Vt) {
  __shared__ float tile[64][65];
  const int kt = blockIdx.x, colt = blockIdx.y, ch = blockIdx.z;
  const int t = threadIdx.x;
  const int kbase = kt * 64, col0 = colt * 64;
  {
    const int key = t >> 2, cseg = (t & 3) * 16;
    const int kk = kbase + key;
    float4 v0 = make_float4(0.f, 0.f, 0.f, 0.f), v1 = v0, v2 = v0, v3 = v0;
    if (kk < kChunk) {
      const float* s = Vf + (size_t)(ch * kChunk + kk) * 512 + col0 + cseg;
      v0 = *(const float4*)(s);
      v1 = *(const float4*)(s + 4);
      v2 = *(const float4*)(s + 8);
      v3 = *(const float4*)(s + 12);
    }
    float* tr = &tile[key][cseg];
    tr[0] = v0.x;  tr[1] = v0.y;  tr[2] = v0.z;  tr[3] = v0.w;
    tr[4] = v1.x;  tr[5] = v1.y;  tr[6] = v1.z;  tr[7] = v1.w;
    tr[8] = v2.x;  tr[9] = v2.y;  tr[10] = v2.z; tr[11] = v2.w;
    tr[12] = v3.x; tr[13] = v3.y; tr[14] = v3.z; tr[15] = v3.w;
  }
  __syncthreads();
  {
    const int col = t >> 2, kw = (t & 3) * 16;
    f16x8 h0, h1;
    #pragma unroll
    for (int u = 0; u < 8; u++) h0[u] = (f16)tile[kw + u][col];
    #pragma unroll
    for (int u = 0; u < 8; u++) h1[u] = (f16)tile[kw + 8 + u][col];
    f16* d = Vt + ((size_t)ch * 512 + col0 + col) * kVStride + kbase + kw;
    *(f16x8*)(d) = h0;
    *(f16x8*)(d + 8) = h1;
  }
}

// ---------------------------------------------------------------------------
// Kernel 1: proj = x @ W^T + b   (f16 x3-split MFMA, near-fp32 accuracy)
// qhi = proj * beta * log2(e)  (folds softmax scaling into Q once)
// ---------------------------------------------------------------------------
__global__ __launch_bounds__(256) void gemm1_kernel(
    const float* __restrict__ x, const float* __restrict__ W,
    const float* __restrict__ bias, const float* __restrict__ beta_p,
    float* __restrict__ proj, f16* __restrict__ qhi)
{
  __shared__ f16 xh[2][64][40], xl[2][64][40], wh[2][64][40], wl[2][64][40];
  const int t = threadIdx.x;
  const int lane = t & 63, w = t >> 6;
  const int wr = w >> 1, wc = w & 1;
  const int g = lane >> 4, j = lane & 15;
  const int m0 = blockIdx.x * 64, n0 = blockIdx.y * 64;
  const int srow = t >> 2;
  const int soff = (t & 3) * 8;
  const float bscale = beta_p[0] * 1.44269504f;

  const f32x4 fzero = {0.f, 0.f, 0.f, 0.f};
  f32x4 acc[2][2], acc2[2][2];
  #pragma unroll
  for (int a = 0; a < 2; a++)
    #pragma unroll
    for (int bb = 0; bb < 2; bb++) { acc[a][bb] = fzero; acc2[a][bb] = fzero; }

  auto stage = [&](int k0s, int buf) {
    const float* xs  = x + (size_t)(m0 + srow) * 1024 + k0s + soff;
    const float* wsr = W + (size_t)(n0 + srow) * 1024 + k0s + soff;
    f16x8 hx, lx, hw, lw;
    #pragma unroll
    for (int i = 0; i < 8; i++) {
      float v = xs[i];
      f16 h = (f16)v;
      hx[i] = h;
      lx[i] = (f16)((v - (float)h) * 2048.0f);
      float u = wsr[i];
      f16 hu = (f16)u;
      hw[i] = hu;
      lw[i] = (f16)((u - (float)hu) * 2048.0f);
    }
    *(f16x8*)&xh[buf][srow][soff] = hx;
    *(f16x8*)&xl[buf][srow][soff] = lx;
    *(f16x8*)&wh[buf][srow][soff] = hw;
    *(f16x8*)&wl[buf][srow][soff] = lw;
  };

  stage(0, 0);
  for (int ks = 0; ks < 32; ks++) {
    __syncthreads();
    if (ks < 31) stage((ks + 1) * 32, (ks + 1) & 1);
    const int buf = ks & 1;
    f16x8 ah[2], al[2], bh[2], bl[2];
    #pragma unroll
    for (int mf = 0; mf < 2; mf++) {
      const int r = wr * 32 + mf * 16 + j;
      ah[mf] = *(const f16x8*)&xh[buf][r][g * 8];
      al[mf] = *(const f16x8*)&xl[buf][r][g * 8];
      const int cc = wc * 32 + mf * 16 + j;
      bh[mf] = *(const f16x8*)&wh[buf][cc][g * 8];
      bl[mf] = *(const f16x8*)&wl[buf][cc][g * 8];
    }
    #pragma unroll
    for (int mf = 0; mf < 2; mf++)
      #pragma unroll
      for (int nf = 0; nf < 2; nf++) {
        acc[mf][nf]  = MFMA16(ah[mf], bh[nf], acc[mf][nf]);
        acc2[mf][nf] = MFMA16(ah[mf], bl[nf], acc2[mf][nf]);
        acc2[mf][nf] = MFMA16(al[mf], bh[nf], acc2[mf][nf]);
      }
  }

  #pragma unroll
  for (int mf = 0; mf < 2; mf++)
    #pragma unroll
    for (int nf = 0; nf < 2; nf++)
      #pragma unroll
      for (int r = 0; r < 4; r++) {
        const int m = m0 + wr * 32 + mf * 16 + g * 4 + r;
        const int n = n0 + wc * 32 + nf * 16 + j;
        float p = acc[mf][nf][r] + acc2[mf][nf][r] * (1.0f / 2048.0f) + bias[n];
        proj[(size_t)m * 512 + n] = p;
        qhi[(size_t)m * 512 + n] = (f16)(p * bscale);
      }
}

// ---------------------------------------------------------------------------
// Kernel 2: flash attention partial. R5/R11-proven 2-phase schedule:
//   phase B: pvstep(it-1) FIRST, then stageK(it+1), then QK(it) + S-write
//   phase A: stageV(it+1) issue, then dh0 softmax in ONE contiguous block
// Gated cross-half max (rescale iters only); cross-half sum deferred to
// epilogue. 2 barriers/iter; vmcnt counted (4), never drained mid-loop.
// ---------------------------------------------------------------------------
__global__ __launch_bounds__(512, 2) void attn_kernel(
    const f16* __restrict__ K16, const f16* __restrict__ Vt16,
    const f16* __restrict__ qhi_ws,
    float* __restrict__ m_part, float* __restrict__ l_part,
    f16* __restrict__ pvn)
{
  extern __shared__ char smem[];
  const int t = threadIdx.x, lane = t & 63, w = t >> 6;
  const int c = lane & 31, h = lane >> 5;
  const int qb = w & 3, dh = w >> 2;     // QK / softmax roles
  const int qp = w & 1, cq = w >> 1;     // PV roles (cq 0..3)
  const int ch = blockIdx.x & 15, qt = blockIdx.x >> 4;
  const int q0 = qt * 128;

  char* const Kb0 = smem + LDS_K0;
  char* const Kb1 = smem + LDS_K1;
  char* const Vb0 = smem + LDS_V0;
  char* const Vb1 = smem + LDS_V1;
  char* const Sq  = smem + LDS_S + qb * 4096;   // own-qb S-partial slot
  char* const Pq  = smem + LDS_P + qb * 2048;   // own-qb P slot
  float* const facl = (float*)(smem + LDS_FAC);
  int* const flg = (int*)(smem + LDS_FLG);

  // ---- Q -> registers as B-frags: lane holds q-col = qb*32+c, k-chunk h*8.
  f16x8 Qf[16];
  {
    const f16* qsrc = qhi_ws + (size_t)(q0 + qb * 32 + c) * 512 + dh * 256 + h * 8;
    #pragma unroll
    for (int i = 0; i < 16; i++) Qf[i] = *(const f16x8*)(qsrc + i * 16);
  }
  __builtin_amdgcn_sched_barrier(0);

  const char* const Kg = (const char*)K16 + (size_t)(ch * kChunk) * 1024;
  const char* const Vg = (const char*)Vt16 + (size_t)ch * 512 * (kVStride * 2);
  // pre-swizzled V source chunk (matches read-side ((c>>1)&3) XOR)
  const int vlo = (((lane & 3) ^ ((lane >> 3) & 3)) << 4);

  auto stageK = [&](int it2, char* dstbuf) {
    const char* src = Kg + (size_t)(it2 * 32 + w * 4) * 1024 + lane * 16;
    char* dst = dstbuf + (w * 4) * 1040 + lane * 16;
    #pragma unroll
    for (int u = 0; u < 4; u++) gld16(src + u * 1024, dst + u * 1040);
  };
  auto stageV = [&](int it2, char* dstbuf) {
    const char* src = Vg + (size_t)(w * 64 + (lane >> 2)) * (kVStride * 2) + it2 * 64 + vlo;
    char* dst = dstbuf + (w * 4) * 1024 + lane * 16;
    #pragma unroll
    for (int u = 0; u < 4; u++)
      gld16(src + (size_t)(u * 16) * (kVStride * 2), dst + u * 1024);
  };

  // LDS read offsets (bank-conflict-engineered)
  const int kroff = c * 1040 + dh * 512 + h * 16;          // QK A-frag base
  const int vbase = (cq * 128 + c) * 64;                   // PV A-frag base
  const int vswz = ((c >> 1) & 3) << 4;
  const int voff0 = (0 + h * 16) ^ vswz;                   // keys 0..15
  const int voff1 = (32 + h * 16) ^ vswz;                  // keys 16..31
  const char* const slotA = smem + LDS_P + (2 * qp) * 2048 + lane * 16;
  const char* const slotB = smem + LDS_P + (2 * qp + 1) * 2048 + lane * 16;

  f32x16 O[2][4];
  #pragma unroll
  for (int ql = 0; ql < 2; ql++)
    #pragma unroll
    for (int cb = 0; cb < 4; cb++)
      #pragma unroll
      for (int r = 0; r < 16; r++) O[ql][cb][r] = 0.f;
  float mrow = -INFINITY, lrow = 0.f;   // lrow HALF-local (combined in epilogue)

  // PV(prev) step: rescale (flag-gated) + 16 MFMA32 on V buffer `Vp`
  auto pvstep = [&](const char* Vp) {
    const int f0 = flg[2 * qp];
    const int f1 = flg[2 * qp + 1];
    const f16x8 pb00 = *(const f16x8*)(slotA);
    const f16x8 pb01 = *(const f16x8*)(slotA + 1024);
    const f16x8 pb10 = *(const f16x8*)(slotB);
    const f16x8 pb11 = *(const f16x8*)(slotB + 1024);
    if (f0) {
      const float fc0 = facl[(2 * qp) * 32 + c];
      #pragma unroll
      for (int cb = 0; cb < 4; cb++)
        #pragma unroll
        for (int r = 0; r < 16; r++) O[0][cb][r] *= fc0;
    }
    if (f1) {
      const float fc1 = facl[(2 * qp + 1) * 32 + c];
      #pragma unroll
      for (int cb = 0; cb < 4; cb++)
        #pragma unroll
        for (int r = 0; r < 16; r++) O[1][cb][r] *= fc1;
    }
    __builtin_amdgcn_s_setprio(1);
    #pragma unroll
    for (int cb = 0; cb < 4; cb++) {
      f16x8 a0 = *(const f16x8*)(Vp + cb * 2048 + voff0);
      f16x8 a1 = *(const f16x8*)(Vp + cb * 2048 + voff1);
      O[0][cb] = MFMA32(a0, pb00, O[0][cb]);
      O[0][cb] = MFMA32(a1, pb01, O[0][cb]);
      O[1][cb] = MFMA32(a0, pb10, O[1][cb]);
      O[1][cb] = MFMA32(a1, pb11, O[1][cb]);
    }
    __builtin_amdgcn_s_setprio(0);
  };

  // prologue: K0 + V0 in flight; wait K0 only
  stageK(0, Kb0);
  stageV(0, Vb0);
  asm volatile("s_waitcnt vmcnt(4)" ::: "memory");
  __builtin_amdgcn_s_barrier();

  for (int it = 0; it < kNit; it++) {
    const int p = it & 1;
    const char* const Kp = (p ? Kb1 : Kb0) + kroff;

    // ================= phase B: PV(it-1) first, then QK(it) =================
    if (it > 0) pvstep((p ? Vb0 : Vb1) + vbase);   // V[it-1] lives in buf p^1
    if (it + 1 < kNit) stageK(it + 1, p ? Kb0 : Kb1);

    f32x16 S;
    #pragma unroll
    for (int r = 0; r < 16; r++) S[r] = 0.f;
    __builtin_amdgcn_s_setprio(1);
    #pragma unroll
    for (int i = 0; i < 16; i++) {
      f16x8 a = *(const f16x8*)(Kp + i * 32);
      S = MFMA32(a, Qf[i], S);
    }
    __builtin_amdgcn_s_setprio(0);

    if (dh == 1) {  // write d-partial (f32), lane-major, conflict-free
      f32x4 v0 = {S[0], S[1], S[2], S[3]};
      f32x4 v1 = {S[4], S[5], S[6], S[7]};
      f32x4 v2 = {S[8], S[9], S[10], S[11]};
      f32x4 v3 = {S[12], S[13], S[14], S[15]};
      *(f32x4*)(Sq + 0 * 1024 + lane * 16) = v0;
      *(f32x4*)(Sq + 1 * 1024 + lane * 16) = v1;
      *(f32x4*)(Sq + 2 * 1024 + lane * 16) = v2;
      *(f32x4*)(Sq + 3 * 1024 + lane * 16) = v3;
    }
    asm volatile("s_waitcnt lgkmcnt(0)" ::: "memory");
    __builtin_amdgcn_s_barrier();                         // bar-beta

    // ================= phase A: stageV(it+1) + softmax(it) =========
    if (it + 1 < kNit) stageV(it + 1, p ? Vb0 : Vb1);     // after bar: safe vs PV reads

    if (dh == 0) {
      #pragma unroll
      for (int cc = 0; cc < 4; cc++) {
        f32x4 v = *(const f32x4*)(Sq + cc * 1024 + lane * 16);
        S[4 * cc + 0] += v.x; S[4 * cc + 1] += v.y;
        S[4 * cc + 2] += v.z; S[4 * cc + 3] += v.w;
      }
      // S already in log2 domain (beta*log2e folded into qhi)
      if (it == kNit - 1) {
        #pragma unroll
        for (int r = 0; r < 16; r++) {
          const int key = it * 32 + (r & 3) + 8 * (r >> 2) + 4 * h;
          if (key >= kChunk) S[r] = -INFINITY;
        }
      }
      // depth-4 max tree (half-local)
      float t0 = fmaxf(S[0], S[1]),  t1 = fmaxf(S[2], S[3]);
      float t2 = fmaxf(S[4], S[5]),  t3 = fmaxf(S[6], S[7]);
      float t4 = fmaxf(S[8], S[9]),  t5 = fmaxf(S[10], S[11]);
      float t6 = fmaxf(S[12], S[13]), t7 = fmaxf(S[14], S[15]);
      t0 = fmaxf(t0, t1); t2 = fmaxf(t2, t3);
      t4 = fmaxf(t4, t5); t6 = fmaxf(t6, t7);
      t0 = fmaxf(t0, t2); t4 = fmaxf(t4, t6);
      float pm = fmaxf(t0, t4);
      // __any spans all 64 lanes -> half-local pm suffices as trigger
      const int need = __any(pm > mrow + 11.5416f);       // defer-max (T13, =e^8)
      float fc = 1.0f;
      if (need) {
        pm = fmaxf(pm, __shfl_xor(pm, 32));               // full-row max (rare)
        const float mn = fmaxf(mrow, pm);
        fc = exp2f(mrow - mn);
        mrow = mn;
      }
      float pr[16];
      #pragma unroll
      for (int r = 0; r < 16; r++) pr[r] = exp2f(S[r] - mrow);
      // depth-4 sum tree; lrow stays HALF-local (combined once in epilogue)
      float s0 = (pr[0] + pr[1]) + (pr[2] + pr[3]);
      float s1 = (pr[4] + pr[5]) + (pr[6] + pr[7]);
      float s2 = (pr[8] + pr[9]) + (pr[10] + pr[11]);
      float s3 = (pr[12] + pr[13]) + (pr[14] + pr[15]);
      float rs = (s0 + s1) + (s2 + s3);
      lrow = lrow * fc + rs;
      // build PV B-frags (pack + half-shuffle + select; known-good layout)
      unsigned pA0 = pk2(pr[0], pr[1]),  pA1 = pk2(pr[2], pr[3]);
      unsigned pB0 = pk2(pr[4], pr[5]),  pB1 = pk2(pr[6], pr[7]);
      unsigned pC0 = pk2(pr[8], pr[9]),  pC1 = pk2(pr[10], pr[11]);
      unsigned pD0 = pk2(pr[12], pr[13]), pD1 = pk2(pr[14], pr[15]);
      unsigned sA0 = __shfl_xor(pA0, 32), sA1 = __shfl_xor(pA1, 32);
      unsigned sB0 = __shfl_xor(pB0, 32), sB1 = __shfl_xor(pB1, 32);
      unsigned sC0 = __shfl_xor(pC0, 32), sC1 = __shfl_xor(pC1, 32);
      unsigned sD0 = __shfl_xor(pD0, 32), sD1 = __shfl_xor(pD1, 32);
      u32x4 B0, B1;
      B0[0] = h ? sB0 : pA0;  B0[1] = h ? sB1 : pA1;
      B0[2] = h ? pB0 : sA0;  B0[3] = h ? pB1 : sA1;
      B1[0] = h ? sD0 : pC0;  B1[1] = h ? sD1 : pC1;
      B1[2] = h ? pD0 : sC0;  B1[3] = h ? pD1 : sC1;
      *(u32x4*)(Pq + lane * 16) = B0;
      *(u32x4*)(Pq + 1024 + lane * 16) = B1;
      if (need && h == 0) facl[qb * 32 + c] = fc;
      if (lane == 0) flg[qb] = need;
    }
    if (it + 1 < kNit)
      asm volatile("s_waitcnt lgkmcnt(0) vmcnt(4)" ::: "memory");  // K(it+1)+V(it) landed
    else
      asm volatile("s_waitcnt lgkmcnt(0) vmcnt(0)" ::: "memory");
    __builtin_amdgcn_s_barrier();                         // bar-alpha
  }

  // final PV of the last slab (V[kNit-1] in buffer (kNit-1)&1)
  pvstep((((kNit - 1) & 1) ? Vb1 : Vb0) + vbase);

  // ---------------- epilogue ----------------
  asm volatile("s_waitcnt lgkmcnt(0)" ::: "memory");
  __builtin_amdgcn_s_barrier();   // all pvstep facl/P reads done before overwrite
  if (dh == 0) {
    lrow += __shfl_xor(lrow, 32);   // combine half-local sums ONCE
    const float iv = 1.0f / lrow;
    if (lane < 32) {
      m_part[ch * kB + q0 + qb * 32 + c] = mrow;
      l_part[ch * kB + q0 + qb * 32 + c] = lrow;
      facl[qb * 32 + c] = iv;
    }
  }
  asm volatile("s_waitcnt lgkmcnt(0)" ::: "memory");
  __builtin_amdgcn_s_barrier();
  const float iv0 = facl[(2 * qp) * 32 + c];
  const float iv1 = facl[(2 * qp + 1) * 32 + c];

  const size_t pvb = ((size_t)ch * kB + q0) * 512;
  #pragma unroll
  for (int ql = 0; ql < 2; ql++) {
    const int qrow = (2 * qp + ql) * 32 + c;
    const float iv = ql ? iv1 : iv0;
    #pragma unroll
    for (int cb = 0; cb < 4; cb++) {
      const int C = cq * 128 + cb * 32;
      #pragma unroll
      for (int a = 0; a < 4; a++) {
        unsigned lo = pk2(O[ql][cb][4 * a + 0] * iv, O[ql][cb][4 * a + 1] * iv);
        unsigned hi = pk2(O[ql][cb][4 * a + 2] * iv, O[ql][cb][4 * a + 3] * iv);
        u32x2 v = {lo, hi};
        *(u32x2*)(pvn + pvb + (size_t)qrow * 512 + C + 8 * a + 4 * h) = v;
      }
    }
  }
}

// ---------------------------------------------------------------------------
// Kernel 3: combine (m in log2 domain):
//   out = proj + alpha * (sum_c g_c l_c pvn_c) / (sum_c g_c l_c), g_c = 2^(m_c-M)
// ---------------------------------------------------------------------------
__global__ __launch_bounds__(256) void combine_kernel(
    const float* __restrict__ proj, const float* __restrict__ m_part,
    const float* __restrict__ l_part, const f16* __restrict__ pvn,
    const float* __restrict__ alpha_p, float* __restrict__ out)
{
  const int row = blockIdx.x;
  const int t = threadIdx.x;
  const float alpha = alpha_p[0];
  float M = -INFINITY;
  #pragma unroll
  for (int c = 0; c < kNch; c++) M = fmaxf(M, m_part[c * kB + row]);
  float gl[kNch];
  float T = 0.f;
  #pragma unroll
  for (int c = 0; c < kNch; c++) {
    gl[c] = exp2f(m_part[c * kB + row] - M) * l_part[c * kB + row];
    T += gl[c];
  }
  const float s = alpha / T;
  #pragma unroll
  for (int half = 0; half < 2; half++) {
    const int col = t + half * 256;
    float acc = 0.f;
    #pragma unroll
    for (int c = 0; c < kNch; c++)
      acc += gl[c] * (float)pvn[((size_t)c * kB + row) * 512 + col];
    out[(size_t)row * 512 + col] = proj[(size_t)row * 512 + col] + acc * s;
  }
}

// ---------------------------------------------------------------------------
extern "C" void kernel_launch(void* const* d_in, const int* in_sizes, int n_in,
                              void* d_out, int out_size, void* d_ws, size_t ws_size,
                              hipStream_t stream) {
  (void)in_sizes; (void)n_in; (void)out_size; (void)ws_size;
  const float* x     = (const float*)d_in[0];
  const float* W     = (const float*)d_in[1];
  const float* bias  = (const float*)d_in[2];
  const float* cimg  = (const float*)d_in[3];
  const float* ctxt  = (const float*)d_in[4];
  const float* beta  = (const float*)d_in[5];
  const float* alpha = (const float*)d_in[6];
  float* out = (float*)d_out;
  char* ws = (char*)d_ws;

  float* proj = (float*)(ws + WS_PROJ);
  f16*   qhi  = (f16*)(ws + WS_QHI);
  float* mp   = (float*)(ws + WS_M);
  float* lp   = (float*)(ws + WS_L);
  f16*   pvn  = (f16*)(ws + WS_PV);
  f16*   K16  = (f16*)(ws + WS_K16);
  f16*   Vt16 = (f16*)(ws + WS_VT);

  (void)hipFuncSetAttribute((const void*)attn_kernel,
                            hipFuncAttributeMaxDynamicSharedMemorySize, LDS_SZ);

  convk_kernel<<<(kKRows * 512 / 8 + 255) / 256, 256, 0, stream>>>(cimg, K16);
  transv_kernel<<<dim3(kVStride / 64, 8, kNch), 256, 0, stream>>>(ctxt, Vt16);
  gemm1_kernel<<<dim3(32, 8), 256, 0, stream>>>(x, W, bias, beta, proj, qhi);
  attn_kernel<<<256, 512, LDS_SZ, stream>>>(K16, Vt16, qhi, mp, lp, pvn);
  combine_kernel<<<2048, 256, 0, stream>>>(proj, mp, lp, pvn, alpha, out);
}

// Round 14
// 361.351 us; speedup vs baseline: 1.2092x; 1.0044x over previous
//
#include <hip/hip_runtime.h>
#include <hip/hip_bf16.h>
#include <math.h>

typedef _Float16 f16;
typedef __attribute__((ext_vector_type(2))) _Float16 f16x2;
typedef __attribute__((ext_vector_type(8))) _Float16 f16x8;
typedef __attribute__((ext_vector_type(4))) float f32x4;
typedef __attribute__((ext_vector_type(16))) float f32x16;
typedef __attribute__((ext_vector_type(4))) unsigned int u32x4;
typedef __attribute__((ext_vector_type(2))) unsigned int u32x2;

#define MFMA16(A, B, C) __builtin_amdgcn_mfma_f32_16x16x32_f16(A, B, C, 0, 0, 0)
#define MFMA32(A, B, C) __builtin_amdgcn_mfma_f32_32x32x16_f16(A, B, C, 0, 0, 0)
#define AS1 __attribute__((address_space(1)))
#define AS3 __attribute__((address_space(3)))

__device__ __forceinline__ void gld16(const char* g, char* l) {
  __builtin_amdgcn_global_load_lds((const AS1 void*)g, (AS3 void*)l, 16, 0, 0);
}

// single-instruction f32 pair -> packed f16 (RTZ); a -> low, b -> high
__device__ __forceinline__ unsigned pk2(float a, float b) {
  auto h = __builtin_amdgcn_cvt_pkrtz(a, b);   // __fp16 ext_vector(2)
  return __builtin_bit_cast(unsigned, h);
}

namespace {
constexpr int kB = 2048;
constexpr int kNch = 16, kChunk = 3125, kNit = 98;   // 98*32 = 3136 >= 3125
constexpr int kKRows = 50176;                        // padded K16 rows
constexpr int kVStride = 3200;                       // padded keys per chunk in Vt16
constexpr int kConvBlocks = kKRows * 512 / 8 / 256;  // 12544
constexpr int kTransBlocks = (kVStride / 64) * 8 * kNch;  // 6400
// workspace layout (bytes)
constexpr size_t WS_PROJ = 0;                                   // [2048][512] f32
constexpr size_t WS_QHI  = WS_PROJ + (size_t)2048 * 512 * 4;    // [2048][512] f16 (beta*log2e scaled)
constexpr size_t WS_M    = WS_QHI + (size_t)2048 * 512 * 2;     // [16][2048] f32 (log2 domain)
constexpr size_t WS_L    = WS_M + (size_t)kNch * kB * 4;        // [16][2048] f32
constexpr size_t WS_PV   = WS_L + (size_t)kNch * kB * 4;        // [16][2048][512] f16 (normalized)
constexpr size_t WS_K16  = WS_PV + (size_t)kNch * kB * 512 * 2; // [50176][512] f16
constexpr size_t WS_VT   = WS_K16 + (size_t)kKRows * 512 * 2;   // [16][512][3200] f16
// attn LDS layout
constexpr int LDS_K0 = 0, LDS_K1 = 33280;            // 2 x (32 rows x 1040B)
constexpr int LDS_V0 = 66560, LDS_V1 = 99328;        // 2 x (512 cols x 64B)
constexpr int LDS_S  = 132096;                       // 4 x 4096 (S-partial exchange)
constexpr int LDS_P  = 148480;                       // 4 x 2048 (P B-frags)
constexpr int LDS_FAC = 156672;                      // 128 f32
constexpr int LDS_FLG = 157184;                      // 4 int
constexpr int LDS_SZ  = 157696;
}

// ---------------------------------------------------------------------------
// Fused prep: blocks [0, kConvBlocks) build K16 (f16 copy, pad rows zeroed);
// blocks [kConvBlocks, +kTransBlocks) build Vt16 (per-chunk f16 transpose).
// ---------------------------------------------------------------------------
__global__ __launch_bounds__(256) void prep_kernel(
    const float* __restrict__ cimg, const float* __restrict__ ctxt,
    f16* __restrict__ K16, f16* __restrict__ Vt)
{
  __shared__ float tile[64][65];
  const int t = threadIdx.x;
  const int b = blockIdx.x;
  if (b < kConvBlocks) {
    const size_t e = ((size_t)b * 256 + t) * 8;
    const int row = (int)(e >> 9);
    float4 a = make_float4(0.f, 0.f, 0.f, 0.f), bb = a;
    if (row < 50000) {
      a = *(const float4*)(cimg + e);
      bb = *(const float4*)(cimg + e + 4);
    }
    f16x8 h;
    h[0] = (f16)a.x;  h[1] = (f16)a.y;  h[2] = (f16)a.z;  h[3] = (f16)a.w;
    h[4] = (f16)bb.x; h[5] = (f16)bb.y; h[6] = (f16)bb.z; h[7] = (f16)bb.w;
    *(f16x8*)(K16 + e) = h;
    return;
  }
  const int b2 = b - kConvBlocks;
  const int kt = b2 % (kVStride / 64);
  const int colt = (b2 / (kVStride / 64)) % 8;
  const int ch = b2 / ((kVStride / 64) * 8);
  const int kbase = kt * 64, col0 = colt * 64;
  {
    const int key = t >> 2, cseg = (t & 3) * 16;
    const int kk = kbase + key;
    float4 v0 = make_float4(0.f, 0.f, 0.f, 0.f), v1 = v0, v2 = v0, v3 = v0;
    if (kk < kChunk) {
      const float* s = ctxt + (size_t)(ch * kChunk + kk) * 512 + col0 + cseg;
      v0 = *(const float4*)(s);
      v1 = *(const float4*)(s + 4);
      v2 = *(const float4*)(s + 8);
      v3 = *(const float4*)(s + 12);
    }
    float* tr = &tile[key][cseg];
    tr[0] = v0.x;  tr[1] = v0.y;  tr[2] = v0.z;  tr[3] = v0.w;
    tr[4] = v1.x;  tr[5] = v1.y;  tr[6] = v1.z;  tr[7] = v1.w;
    tr[8] = v2.x;  tr[9] = v2.y;  tr[10] = v2.z; tr[11] = v2.w;
    tr[12] = v3.x; tr[13] = v3.y; tr[14] = v3.z; tr[15] = v3.w;
  }
  __syncthreads();
  {
    const int col = t >> 2, kw = (t & 3) * 16;
    f16x8 h0, h1;
    #pragma unroll
    for (int u = 0; u < 8; u++) h0[u] = (f16)tile[kw + u][col];
    #pragma unroll
    for (int u = 0; u < 8; u++) h1[u] = (f16)tile[kw + 8 + u][col];
    f16* d = Vt + ((size_t)ch * 512 + col0 + col) * kVStride + kbase + kw;
    *(f16x8*)(d) = h0;
    *(f16x8*)(d + 8) = h1;
  }
}

// ---------------------------------------------------------------------------
// Kernel 1: proj = x @ W^T + b   (f16 x3-split MFMA, near-fp32 accuracy)
// qhi = proj * beta * log2(e)  (folds softmax scaling into Q once)
// ---------------------------------------------------------------------------
__global__ __launch_bounds__(256) void gemm1_kernel(
    const float* __restrict__ x, const float* __restrict__ W,
    const float* __restrict__ bias, const float* __restrict__ beta_p,
    float* __restrict__ proj, f16* __restrict__ qhi)
{
  __shared__ f16 xh[2][64][40], xl[2][64][40], wh[2][64][40], wl[2][64][40];
  const int t = threadIdx.x;
  const int lane = t & 63, w = t >> 6;
  const int wr = w >> 1, wc = w & 1;
  const int g = lane >> 4, j = lane & 15;
  const int m0 = blockIdx.x * 64, n0 = blockIdx.y * 64;
  const int srow = t >> 2;
  const int soff = (t & 3) * 8;
  const float bscale = beta_p[0] * 1.44269504f;

  const f32x4 fzero = {0.f, 0.f, 0.f, 0.f};
  f32x4 acc[2][2], acc2[2][2];
  #pragma unroll
  for (int a = 0; a < 2; a++)
    #pragma unroll
    for (int bb = 0; bb < 2; bb++) { acc[a][bb] = fzero; acc2[a][bb] = fzero; }

  auto stage = [&](int k0s, int buf) {
    const float* xs  = x + (size_t)(m0 + srow) * 1024 + k0s + soff;
    const float* wsr = W + (size_t)(n0 + srow) * 1024 + k0s + soff;
    f16x8 hx, lx, hw, lw;
    #pragma unroll
    for (int i = 0; i < 8; i++) {
      float v = xs[i];
      f16 h = (f16)v;
      hx[i] = h;
      lx[i] = (f16)((v - (float)h) * 2048.0f);
      float u = wsr[i];
      f16 hu = (f16)u;
      hw[i] = hu;
      lw[i] = (f16)((u - (float)hu) * 2048.0f);
    }
    *(f16x8*)&xh[buf][srow][soff] = hx;
    *(f16x8*)&xl[buf][srow][soff] = lx;
    *(f16x8*)&wh[buf][srow][soff] = hw;
    *(f16x8*)&wl[buf][srow][soff] = lw;
  };

  stage(0, 0);
  for (int ks = 0; ks < 32; ks++) {
    __syncthreads();
    if (ks < 31) stage((ks + 1) * 32, (ks + 1) & 1);
    const int buf = ks & 1;
    f16x8 ah[2], al[2], bh[2], bl[2];
    #pragma unroll
    for (int mf = 0; mf < 2; mf++) {
      const int r = wr * 32 + mf * 16 + j;
      ah[mf] = *(const f16x8*)&xh[buf][r][g * 8];
      al[mf] = *(const f16x8*)&xl[buf][r][g * 8];
      const int cc = wc * 32 + mf * 16 + j;
      bh[mf] = *(const f16x8*)&wh[buf][cc][g * 8];
      bl[mf] = *(const f16x8*)&wl[buf][cc][g * 8];
    }
    #pragma unroll
    for (int mf = 0; mf < 2; mf++)
      #pragma unroll
      for (int nf = 0; nf < 2; nf++) {
        acc[mf][nf]  = MFMA16(ah[mf], bh[nf], acc[mf][nf]);
        acc2[mf][nf] = MFMA16(ah[mf], bl[nf], acc2[mf][nf]);
        acc2[mf][nf] = MFMA16(al[mf], bh[nf], acc2[mf][nf]);
      }
  }

  #pragma unroll
  for (int mf = 0; mf < 2; mf++)
    #pragma unroll
    for (int nf = 0; nf < 2; nf++)
      #pragma unroll
      for (int r = 0; r < 4; r++) {
        const int m = m0 + wr * 32 + mf * 16 + g * 4 + r;
        const int n = n0 + wc * 32 + nf * 16 + j;
        float p = acc[mf][nf][r] + acc2[mf][nf][r] * (1.0f / 2048.0f) + bias[n];
        proj[(size_t)m * 512 + n] = p;
        qhi[(size_t)m * 512 + n] = (f16)(p * bscale);
      }
}

// ---------------------------------------------------------------------------
// Kernel 2: flash attention partial. R5/R13-proven 2-phase schedule:
//   phase B: pvstep(it-1) FIRST, then stageK(it+1), then QK(it) + S-write
//   phase A: stageV(it+1) issue, then dh0 softmax in ONE contiguous block
// Gated cross-half max (rescale iters only); cross-half sum deferred to
// epilogue. 2 barriers/iter; vmcnt counted (4), never drained mid-loop.
// ---------------------------------------------------------------------------
__global__ __launch_bounds__(512, 2) void attn_kernel(
    const f16* __restrict__ K16, const f16* __restrict__ Vt16,
    const f16* __restrict__ qhi_ws,
    float* __restrict__ m_part, float* __restrict__ l_part,
    f16* __restrict__ pvn)
{
  extern __shared__ char smem[];
  const int t = threadIdx.x, lane = t & 63, w = t >> 6;
  const int c = lane & 31, h = lane >> 5;
  const int qb = w & 3, dh = w >> 2;     // QK / softmax roles
  const int qp = w & 1, cq = w >> 1;     // PV roles (cq 0..3)
  const int ch = blockIdx.x & 15, qt = blockIdx.x >> 4;
  const int q0 = qt * 128;

  char* const Kb0 = smem + LDS_K0;
  char* const Kb1 = smem + LDS_K1;
  char* const Vb0 = smem + LDS_V0;
  char* const Vb1 = smem + LDS_V1;
  char* const Sq  = smem + LDS_S + qb * 4096;   // own-qb S-partial slot
  char* const Pq  = smem + LDS_P + qb * 2048;   // own-qb P slot
  float* const facl = (float*)(smem + LDS_FAC);
  int* const flg = (int*)(smem + LDS_FLG);

  // ---- Q -> registers as B-frags: lane holds q-col = qb*32+c, k-chunk h*8.
  f16x8 Qf[16];
  {
    const f16* qsrc = qhi_ws + (size_t)(q0 + qb * 32 + c) * 512 + dh * 256 + h * 8;
    #pragma unroll
    for (int i = 0; i < 16; i++) Qf[i] = *(const f16x8*)(qsrc + i * 16);
  }
  __builtin_amdgcn_sched_barrier(0);

  const char* const Kg = (const char*)K16 + (size_t)(ch * kChunk) * 1024;
  const char* const Vg = (const char*)Vt16 + (size_t)ch * 512 * (kVStride * 2);
  // pre-swizzled V source chunk (matches read-side ((c>>1)&3) XOR)
  const int vlo = (((lane & 3) ^ ((lane >> 3) & 3)) << 4);

  auto stageK = [&](int it2, char* dstbuf) {
    const char* src = Kg + (size_t)(it2 * 32 + w * 4) * 1024 + lane * 16;
    char* dst = dstbuf + (w * 4) * 1040 + lane * 16;
    #pragma unroll
    for (int u = 0; u < 4; u++) gld16(src + u * 1024, dst + u * 1040);
  };
  auto stageV = [&](int it2, char* dstbuf) {
    const char* src = Vg + (size_t)(w * 64 + (lane >> 2)) * (kVStride * 2) + it2 * 64 + vlo;
    char* dst = dstbuf + (w * 4) * 1024 + lane * 16;
    #pragma unroll
    for (int u = 0; u < 4; u++)
      gld16(src + (size_t)(u * 16) * (kVStride * 2), dst + u * 1024);
  };

  // LDS read offsets (bank-conflict-engineered)
  const int kroff = c * 1040 + dh * 512 + h * 16;          // QK A-frag base
  const int vbase = (cq * 128 + c) * 64;                   // PV A-frag base
  const int vswz = ((c >> 1) & 3) << 4;
  const int voff0 = (0 + h * 16) ^ vswz;                   // keys 0..15
  const int voff1 = (32 + h * 16) ^ vswz;                  // keys 16..31
  const char* const slotA = smem + LDS_P + (2 * qp) * 2048 + lane * 16;
  const char* const slotB = smem + LDS_P + (2 * qp + 1) * 2048 + lane * 16;

  f32x16 O[2][4];
  #pragma unroll
  for (int ql = 0; ql < 2; ql++)
    #pragma unroll
    for (int cb = 0; cb < 4; cb++)
      #pragma unroll
      for (int r = 0; r < 16; r++) O[ql][cb][r] = 0.f;
  float mrow = -INFINITY, lrow = 0.f;   // lrow HALF-local (combined in epilogue)

  // PV(prev) step: rescale (flag-gated) + 16 MFMA32 on V buffer `Vp`
  auto pvstep = [&](const char* Vp) {
    const int f0 = flg[2 * qp];
    const int f1 = flg[2 * qp + 1];
    const f16x8 pb00 = *(const f16x8*)(slotA);
    const f16x8 pb01 = *(const f16x8*)(slotA + 1024);
    const f16x8 pb10 = *(const f16x8*)(slotB);
    const f16x8 pb11 = *(const f16x8*)(slotB + 1024);
    if (f0) {
      const float fc0 = facl[(2 * qp) * 32 + c];
      #pragma unroll
      for (int cb = 0; cb < 4; cb++)
        #pragma unroll
        for (int r = 0; r < 16; r++) O[0][cb][r] *= fc0;
    }
    if (f1) {
      const float fc1 = facl[(2 * qp + 1) * 32 + c];
      #pragma unroll
      for (int cb = 0; cb < 4; cb++)
        #pragma unroll
        for (int r = 0; r < 16; r++) O[1][cb][r] *= fc1;
    }
    __builtin_amdgcn_s_setprio(1);
    #pragma unroll
    for (int cb = 0; cb < 4; cb++) {
      f16x8 a0 = *(const f16x8*)(Vp + cb * 2048 + voff0);
      f16x8 a1 = *(const f16x8*)(Vp + cb * 2048 + voff1);
      O[0][cb] = MFMA32(a0, pb00, O[0][cb]);
      O[0][cb] = MFMA32(a1, pb01, O[0][cb]);
      O[1][cb] = MFMA32(a0, pb10, O[1][cb]);
      O[1][cb] = MFMA32(a1, pb11, O[1][cb]);
    }
    __builtin_amdgcn_s_setprio(0);
  };

  // prologue: K0 + V0 in flight; wait K0 only
  stageK(0, Kb0);
  stageV(0, Vb0);
  asm volatile("s_waitcnt vmcnt(4)" ::: "memory");
  __builtin_amdgcn_s_barrier();

  for (int it = 0; it < kNit; it++) {
    const int p = it & 1;
    const char* const Kp = (p ? Kb1 : Kb0) + kroff;

    // ================= phase B: PV(it-1) first, then QK(it) =================
    if (it > 0) pvstep((p ? Vb0 : Vb1) + vbase);   // V[it-1] lives in buf p^1
    if (it + 1 < kNit) stageK(it + 1, p ? Kb0 : Kb1);

    f32x16 S;
    #pragma unroll
    for (int r = 0; r < 16; r++) S[r] = 0.f;
    __builtin_amdgcn_s_setprio(1);
    #pragma unroll
    for (int i = 0; i < 16; i++) {
      f16x8 a = *(const f16x8*)(Kp + i * 32);
      S = MFMA32(a, Qf[i], S);
    }
    __builtin_amdgcn_s_setprio(0);

    if (dh == 1) {  // write d-partial (f32), lane-major, conflict-free
      f32x4 v0 = {S[0], S[1], S[2], S[3]};
      f32x4 v1 = {S[4], S[5], S[6], S[7]};
      f32x4 v2 = {S[8], S[9], S[10], S[11]};
      f32x4 v3 = {S[12], S[13], S[14], S[15]};
      *(f32x4*)(Sq + 0 * 1024 + lane * 16) = v0;
      *(f32x4*)(Sq + 1 * 1024 + lane * 16) = v1;
      *(f32x4*)(Sq + 2 * 1024 + lane * 16) = v2;
      *(f32x4*)(Sq + 3 * 1024 + lane * 16) = v3;
    }
    asm volatile("s_waitcnt lgkmcnt(0)" ::: "memory");
    __builtin_amdgcn_s_barrier();                         // bar-beta

    // ================= phase A: stageV(it+1) + softmax(it) =========
    if (it + 1 < kNit) stageV(it + 1, p ? Vb0 : Vb1);     // after bar: safe vs PV reads

    if (dh == 0) {
      #pragma unroll
      for (int cc = 0; cc < 4; cc++) {
        f32x4 v = *(const f32x4*)(Sq + cc * 1024 + lane * 16);
        S[4 * cc + 0] += v.x; S[4 * cc + 1] += v.y;
        S[4 * cc + 2] += v.z; S[4 * cc + 3] += v.w;
      }
      // S already in log2 domain (beta*log2e folded into qhi)
      if (it == kNit - 1) {
        #pragma unroll
        for (int r = 0; r < 16; r++) {
          const int key = it * 32 + (r & 3) + 8 * (r >> 2) + 4 * h;
          if (key >= kChunk) S[r] = -INFINITY;
        }
      }
      // depth-4 max tree (half-local)
      float t0 = fmaxf(S[0], S[1]),  t1 = fmaxf(S[2], S[3]);
      float t2 = fmaxf(S[4], S[5]),  t3 = fmaxf(S[6], S[7]);
      float t4 = fmaxf(S[8], S[9]),  t5 = fmaxf(S[10], S[11]);
      float t6 = fmaxf(S[12], S[13]), t7 = fmaxf(S[14], S[15]);
      t0 = fmaxf(t0, t1); t2 = fmaxf(t2, t3);
      t4 = fmaxf(t4, t5); t6 = fmaxf(t6, t7);
      t0 = fmaxf(t0, t2); t4 = fmaxf(t4, t6);
      float pm = fmaxf(t0, t4);
      // __any spans all 64 lanes -> half-local pm suffices as trigger
      const int need = __any(pm > mrow + 11.5416f);       // defer-max (T13, =e^8)
      float fc = 1.0f;
      if (need) {
        pm = fmaxf(pm, __shfl_xor(pm, 32));               // full-row max (rare)
        const float mn = fmaxf(mrow, pm);
        fc = exp2f(mrow - mn);
        mrow = mn;
      }
      float pr[16];
      #pragma unroll
      for (int r = 0; r < 16; r++) pr[r] = exp2f(S[r] - mrow);
      // depth-4 sum tree; lrow stays HALF-local (combined once in epilogue)
      float s0 = (pr[0] + pr[1]) + (pr[2] + pr[3]);
      float s1 = (pr[4] + pr[5]) + (pr[6] + pr[7]);
      float s2 = (pr[8] + pr[9]) + (pr[10] + pr[11]);
      float s3 = (pr[12] + pr[13]) + (pr[14] + pr[15]);
      float rs = (s0 + s1) + (s2 + s3);
      lrow = lrow * fc + rs;
      // build PV B-frags (pack + half-shuffle + select; known-good layout)
      unsigned pA0 = pk2(pr[0], pr[1]),  pA1 = pk2(pr[2], pr[3]);
      unsigned pB0 = pk2(pr[4], pr[5]),  pB1 = pk2(pr[6], pr[7]);
      unsigned pC0 = pk2(pr[8], pr[9]),  pC1 = pk2(pr[10], pr[11]);
      unsigned pD0 = pk2(pr[12], pr[13]), pD1 = pk2(pr[14], pr[15]);
      unsigned sA0 = __shfl_xor(pA0, 32), sA1 = __shfl_xor(pA1, 32);
      unsigned sB0 = __shfl_xor(pB0, 32), sB1 = __shfl_xor(pB1, 32);
      unsigned sC0 = __shfl_xor(pC0, 32), sC1 = __shfl_xor(pC1, 32);
      unsigned sD0 = __shfl_xor(pD0, 32), sD1 = __shfl_xor(pD1, 32);
      u32x4 B0, B1;
      B0[0] = h ? sB0 : pA0;  B0[1] = h ? sB1 : pA1;
      B0[2] = h ? pB0 : sA0;  B0[3] = h ? pB1 : sA1;
      B1[0] = h ? sD0 : pC0;  B1[1] = h ? sD1 : pC1;
      B1[2] = h ? pD0 : sC0;  B1[3] = h ? pD1 : sC1;
      *(u32x4*)(Pq + lane * 16) = B0;
      *(u32x4*)(Pq + 1024 + lane * 16) = B1;
      if (need && h == 0) facl[qb * 32 + c] = fc;
      if (lane == 0) flg[qb] = need;
    }
    if (it + 1 < kNit)
      asm volatile("s_waitcnt lgkmcnt(0) vmcnt(4)" ::: "memory");  // K(it+1)+V(it) landed
    else
      asm volatile("s_waitcnt lgkmcnt(0) vmcnt(0)" ::: "memory");
    __builtin_amdgcn_s_barrier();                         // bar-alpha
  }

  // final PV of the last slab (V[kNit-1] in buffer (kNit-1)&1)
  pvstep((((kNit - 1) & 1) ? Vb1 : Vb0) + vbase);

  // ---------------- epilogue ----------------
  asm volatile("s_waitcnt lgkmcnt(0)" ::: "memory");
  __builtin_amdgcn_s_barrier();   // all pvstep facl/P reads done before overwrite
  if (dh == 0) {
    lrow += __shfl_xor(lrow, 32);   // combine half-local sums ONCE
    const float iv = 1.0f / lrow;
    if (lane < 32) {
      m_part[ch * kB + q0 + qb * 32 + c] = mrow;
      l_part[ch * kB + q0 + qb * 32 + c] = lrow;
      facl[qb * 32 + c] = iv;
    }
  }
  asm volatile("s_waitcnt lgkmcnt(0)" ::: "memory");
  __builtin_amdgcn_s_barrier();
  const float iv0 = facl[(2 * qp) * 32 + c];
  const float iv1 = facl[(2 * qp + 1) * 32 + c];

  const size_t pvb = ((size_t)ch * kB + q0) * 512;
  #pragma unroll
  for (int ql = 0; ql < 2; ql++) {
    const int qrow = (2 * qp + ql) * 32 + c;
    const float iv = ql ? iv1 : iv0;
    #pragma unroll
    for (int cb = 0; cb < 4; cb++) {
      const int C = cq * 128 + cb * 32;
      #pragma unroll
      for (int a = 0; a < 4; a++) {
        unsigned lo = pk2(O[ql][cb][4 * a + 0] * iv, O[ql][cb][4 * a + 1] * iv);
        unsigned hi = pk2(O[ql][cb][4 * a + 2] * iv, O[ql][cb][4 * a + 3] * iv);
        u32x2 v = {lo, hi};
        *(u32x2*)(pvn + pvb + (size_t)qrow * 512 + C + 8 * a + 4 * h) = v;
      }
    }
  }
}

// ---------------------------------------------------------------------------
// Kernel 3: combine (m in log2 domain), 2 adjacent cols per thread (u32 loads):
//   out = proj + alpha * (sum_c g_c l_c pvn_c) / (sum_c g_c l_c), g_c = 2^(m_c-M)
// ---------------------------------------------------------------------------
__global__ __launch_bounds__(256) void combine_kernel(
    const float* __restrict__ proj, const float* __restrict__ m_part,
    const float* __restrict__ l_part, const f16* __restrict__ pvn,
    const float* __restrict__ alpha_p, float* __restrict__ out)
{
  const int row = blockIdx.x;
  const int t = threadIdx.x;
  const float alpha = alpha_p[0];
  float M = -INFINITY;
  #pragma unroll
  for (int c = 0; c < kNch; c++) M = fmaxf(M, m_part[c * kB + row]);
  float gl[kNch];
  float T = 0.f;
  #pragma unroll
  for (int c = 0; c < kNch; c++) {
    gl[c] = exp2f(m_part[c * kB + row] - M) * l_part[c * kB + row];
    T += gl[c];
  }
  const float s = alpha / T;
  const int col = t * 2;
  float a0 = 0.f, a1 = 0.f;
  #pragma unroll
  for (int c = 0; c < kNch; c++) {
    const unsigned pv = *(const unsigned*)(pvn + ((size_t)c * kB + row) * 512 + col);
    const f16x2 v = __builtin_bit_cast(f16x2, pv);
    a0 += gl[c] * (float)v[0];
    a1 += gl[c] * (float)v[1];
  }
  const float2 pj = *(const float2*)(proj + (size_t)row * 512 + col);
  float2 o;
  o.x = pj.x + a0 * s;
  o.y = pj.y + a1 * s;
  *(float2*)(out + (size_t)row * 512 + col) = o;
}

// ---------------------------------------------------------------------------
extern "C" void kernel_launch(void* const* d_in, const int* in_sizes, int n_in,
                              void* d_out, int out_size, void* d_ws, size_t ws_size,
                              hipStream_t stream) {
  (void)in_sizes; (void)n_in; (void)out_size; (void)ws_size;
  const float* x     = (const float*)d_in[0];
  const float* W     = (const float*)d_in[1];
  const float* bias  = (const float*)d_in[2];
  const float* cimg  = (const float*)d_in[3];
  const float* ctxt  = (const float*)d_in[4];
  const float* beta  = (const float*)d_in[5];
  const float* alpha = (const float*)d_in[6];
  float* out = (float*)d_out;
  char* ws = (char*)d_ws;

  float* proj = (float*)(ws + WS_PROJ);
  f16*   qhi  = (f16*)(ws + WS_QHI);
  float* mp   = (float*)(ws + WS_M);
  float* lp   = (float*)(ws + WS_L);
  f16*   pvn  = (f16*)(ws + WS_PV);
  f16*   K16  = (f16*)(ws + WS_K16);
  f16*   Vt16 = (f16*)(ws + WS_VT);

  (void)hipFuncSetAttribute((const void*)attn_kernel,
                            hipFuncAttributeMaxDynamicSharedMemorySize, LDS_SZ);

  prep_kernel<<<kConvBlocks + kTransBlocks, 256, 0, stream>>>(cimg, ctxt, K16, Vt16);
  gemm1_kernel<<<dim3(32, 8), 256, 0, stream>>>(x, W, bias, beta, proj, qhi);
  attn_kernel<<<256, 512, LDS_SZ, stream>>>(K16, Vt16, qhi, mp, lp, pvn);
  combine_kernel<<<2048, 256, 0, stream>>>(proj, mp, lp, pvn, alpha, out);
}